// Round 1
// baseline (147.459 us; speedup 1.0000x reference)
//
#include <hip/hip_runtime.h>
#include <math.h>

#define NB       1025
#define M        1024      // half-length complex FFT size
#define FFTN     2048
#define HOP      512
#define NFRAMES  4000
#define BATCH    4
#define OUT_T    2047488   // (F-1)*hop + N - 2*half = 3999*512
#define PI_F     3.14159265358979323846f

__device__ __forceinline__ float2 cmul(float2 a, float2 b) {
    return make_float2(a.x*b.x - a.y*b.y, a.x*b.y + a.y*b.x);
}

// One block per frame: build packed spectrum Z, 1024-pt radix-4 Stockham IFFT
// in LDS, unpack to 2048 real samples, window, atomic overlap-add into out.
__global__ __launch_bounds__(256) void istft_fft_kernel(
    const float* __restrict__ sr, const float* __restrict__ si,
    float* __restrict__ out)
{
    __shared__ float2 bufA[M];
    __shared__ float2 bufB[M];

    const int blk = blockIdx.x;
    const int b   = blk / NFRAMES;
    const int f   = blk - b * NFRAMES;
    const float* __restrict__ xr = sr + (size_t)blk * NB;
    const float* __restrict__ xi = si + (size_t)blk * NB;
    const int j = threadIdx.x;

    // ---- Build Z[k] = E[k] + i*O[k]  (C2R packing; imag of bins 0,1024 ignored)
    #pragma unroll
    for (int kk = 0; kk < 4; ++kk) {
        int k = j + kk * 256;
        float ar = xr[k],  ai = xi[k];
        int   mk = M - k;                 // 1..1024
        float br = xr[mk], bi = xi[mk];
        if (k == 0) { ai = 0.f; bi = 0.f; }   // numpy irfft ignores imag of DC & Nyquist
        float Er = 0.5f * (ar + br);
        float Ei = 0.5f * (ai - bi);
        float Dr = 0.5f * (ar - br);
        float Di = 0.5f * (ai + bi);
        float s, c;
        __sincosf(PI_F * (float)k * (1.0f / (float)M), &s, &c);   // e^{+i pi k / M}
        float Or = Dr * c - Di * s;
        float Oi = Dr * s + Di * c;
        bufA[k] = make_float2(Er - Oi, Ei + Or);
    }
    __syncthreads();

    // ---- 5 radix-4 Stockham stages (inverse: sign = +1), ping-pong LDS
    float2* src = bufA;
    float2* dst = bufB;
    #pragma unroll
    for (int st = 0; st < 5; ++st) {
        const int Ns = 1 << (2 * st);
        float2 v0 = src[j];
        float2 v1 = src[j + 256];
        float2 v2 = src[j + 512];
        float2 v3 = src[j + 768];
        int jm = j & (Ns - 1);
        float ang = (0.5f * PI_F / (float)Ns) * (float)jm;   // 2*pi*jm/(4*Ns)
        float s1, c1;
        __sincosf(ang, &s1, &c1);
        float2 w1 = make_float2(c1, s1);
        float2 w2 = cmul(w1, w1);
        float2 w3 = cmul(w2, w1);
        v1 = cmul(v1, w1);
        v2 = cmul(v2, w2);
        v3 = cmul(v3, w3);
        float2 t0 = make_float2(v0.x + v2.x, v0.y + v2.y);
        float2 t1 = make_float2(v0.x - v2.x, v0.y - v2.y);
        float2 t2 = make_float2(v1.x + v3.x, v1.y + v3.y);
        float2 t3 = make_float2(v1.x - v3.x, v1.y - v3.y);
        int idxD = ((j >> (2 * st)) << (2 * st + 2)) + jm;
        dst[idxD         ] = make_float2(t0.x + t2.x, t0.y + t2.y);   // y0
        dst[idxD +     Ns] = make_float2(t1.x - t3.y, t1.y + t3.x);   // y1 = t1 + i*t3
        dst[idxD + 2 * Ns] = make_float2(t0.x - t2.x, t0.y - t2.y);   // y2
        dst[idxD + 3 * Ns] = make_float2(t1.x + t3.y, t1.y - t3.x);   // y3 = t1 - i*t3
        float2* tmp = src; src = dst; dst = tmp;
        __syncthreads();
    }
    // result g[n] now in src (natural order); x[2n]=Re g, x[2n+1]=Im g

    // ---- unpack to real time-domain samples in the other buffer
    float* time = (float*)dst;
    #pragma unroll
    for (int kk = 0; kk < 4; ++kk) {
        int n = j + kk * 256;
        float2 g = src[n];
        time[2 * n    ] = g.x;
        time[2 * n + 1] = g.y;
    }
    __syncthreads();

    // ---- window (hann^1), scale 1/M, atomic overlap-add (coalesced across wave)
    const float inv = 1.0f / (float)M;
    float* outb = out + (size_t)b * OUT_T;
    const int base = f * HOP - (FFTN / 2);   // trim half=1024
    #pragma unroll
    for (int q = 0; q < 8; ++q) {
        int t = j + q * 256;
        float sw = __sinf((PI_F / (float)FFTN) * (float)t);  // w = sin^2(pi t / N)
        float w  = sw * sw;
        float val = time[t] * w * inv;
        int p = base + t;
        if ((unsigned)p < (unsigned)OUT_T) {
            atomicAdd(outb + p, val);
        }
    }
}

// Divide by window_sumsquare (computed analytically: <=4 overlapping hann^2 terms)
__global__ __launch_bounds__(256) void normalize_kernel(float* __restrict__ out, int total)
{
    int idx = blockIdx.x * 256 + threadIdx.x;
    if (idx >= total) return;
    int t_in_b = idx % OUT_T;
    int t  = t_in_b + FFTN / 2;        // position in untrimmed signal
    int fm = t >> 9;                   // t / HOP
    int n0 = t & 511;
    float wsq = 0.f;
    #pragma unroll
    for (int jj = 0; jj < 4; ++jj) {
        int fr = fm - jj;
        if (fr >= 0 && fr < NFRAMES) {
            int n = n0 + (jj << 9);
            float sw = __sinf((PI_F / (float)FFTN) * (float)n);
            float w  = sw * sw;
            wsq += w * w;
        }
    }
    const float tiny = 1.17549435e-38f;   // np.finfo(float32).tiny
    float denom = (wsq > tiny) ? wsq : 1.0f;
    out[idx] /= denom;
}

extern "C" void kernel_launch(void* const* d_in, const int* in_sizes, int n_in,
                              void* d_out, int out_size, void* d_ws, size_t ws_size,
                              hipStream_t stream) {
    const float* sr = (const float*)d_in[0];
    const float* si = (const float*)d_in[1];
    float* out = (float*)d_out;

    // zero the OLA accumulator every call (graph-capture-safe async memset)
    hipMemsetAsync(d_out, 0, (size_t)out_size * sizeof(float), stream);

    istft_fft_kernel<<<BATCH * NFRAMES, 256, 0, stream>>>(sr, si, out);

    int total = out_size;
    normalize_kernel<<<(total + 255) / 256, 256, 0, stream>>>(out, total);
}